// Round 14
// baseline (117.465 us; speedup 1.0000x reference)
//
#include <hip/hip_runtime.h>
#include <hip/hip_fp16.h>

#define N_PY 512
#define IN_F 6
#define OUT_F 64
#define N_CELLS (512 * 512)
#define NCOARSE 256               // coarse bucket = cell >> 10 (1024 cells)
#define NBUCKET 4096              // tile bucket  = cell >> 6   (64 cells)
#define N_SB (NBUCKET * 4)        // fine = (cell>>6)*4 | (cell&3) = 16384
#define CHUNK 2048                // points per passA block
#define BN_EPS 1e-5

// ---------------------------------------------------------------------------
// ws layout:
//   [0, 108)          : 27 floats — moment accumulators (written by passA)
//   [512, 2304)       : float Wp[64*6], float bp[64] — BN-folded (passB blk 0)
//   [4096, 69632)     : int H16[16384]  — global fine histogram
//   [69632, 135172)   : int S[16385]    — excl scan of H16 + sentinel S[16384]=n
//   [135680, 136704)  : int curC[256]   — passA cursors, = S[c*64]
//   [139264, +16n)    : uint4 rec[n]    — coarse-grouped 16B records
//   [139264+16n, +16n): uint4 rec2[n]   — fine-sorted records
// Fine ID is coarse-major, so S (global fine scan) simultaneously provides
// coarse region bounds (S[c*64]) and fine segment bounds — passB needs no
// per-block histogram pass (single-pass scatter).
// ---------------------------------------------------------------------------

__device__ __forceinline__ int fine_id(int cell) {
    return ((cell >> 6) << 2) | (cell & 3);
}

__device__ __forceinline__ unsigned pack2h(float a, float b) {
    __half ha = __float2half_rn(a), hb = __float2half_rn(b);
    unsigned short ua = *reinterpret_cast<unsigned short*>(&ha);
    unsigned short ub = *reinterpret_cast<unsigned short*>(&hb);
    return (unsigned)ua | ((unsigned)ub << 16);
}

__device__ __forceinline__ float2 unpack2h(unsigned u) {
    __half2 h = *reinterpret_cast<__half2*>(&u);
    return __half22float2(h);
}

// ---- 1) global fine histogram from idx only ----
__global__ void __launch_bounds__(256)
pfn_hist16_kernel(const int* __restrict__ idx, int n, int* __restrict__ H16) {
    const int tid = blockIdx.x * blockDim.x + threadIdx.x;
    const int stride = gridDim.x * blockDim.x;
    const int npairs = n >> 1;

    for (int q = tid; q < npairs; q += stride) {
        const int4 ij2 = ((const int4*)idx)[q];
        atomicAdd(&H16[fine_id(ij2.x * N_PY + ij2.y)], 1);
        atomicAdd(&H16[fine_id(ij2.z * N_PY + ij2.w)], 1);
    }
    if ((n & 1) && tid == 0) {
        const int2 ij = ((const int2*)idx)[n - 1];
        atomicAdd(&H16[fine_id(ij.x * N_PY + ij.y)], 1);
    }
}

// ---- 2) exclusive scan of H16 -> S, curC, sentinel (1 block, 1024 thr) ----
__global__ void __launch_bounds__(1024)
pfn_scan16_kernel(const int* __restrict__ H16, int* __restrict__ S,
                  int* __restrict__ curC, int n) {
    const int tid = threadIdx.x;   // 1024 threads x 16 entries
    int v[16];
    const int4* h4 = (const int4*)(H16 + tid * 16);
#pragma unroll
    for (int g = 0; g < 4; ++g) {
        const int4 q = h4[g];
        v[g * 4 + 0] = q.x; v[g * 4 + 1] = q.y;
        v[g * 4 + 2] = q.z; v[g * 4 + 3] = q.w;
    }
    int pre[16];
    int tot = 0;
#pragma unroll
    for (int k = 0; k < 16; ++k) { pre[k] = tot; tot += v[k]; }

    __shared__ int sc[1024];
    sc[tid] = tot;
    __syncthreads();
#pragma unroll
    for (int off = 1; off < 1024; off <<= 1) {
        const int add = (tid >= off) ? sc[tid - off] : 0;
        __syncthreads();
        sc[tid] += add;
        __syncthreads();
    }
    const int excl = sc[tid] - tot;
#pragma unroll
    for (int k = 0; k < 16; ++k)
        S[tid * 16 + k] = excl + pre[k];
    if (tid == 1023) S[N_SB] = n;
    __syncthreads();
    if (tid < NCOARSE) curC[tid] = S[tid * 64];
}

// ---- 3) passA: coarse LDS-staged partition + moment accumulation ----
__global__ void __launch_bounds__(256)
pfn_passA_kernel(const float* __restrict__ x, const int* __restrict__ idx,
                 int* __restrict__ curC, uint4* __restrict__ rec,
                 float* __restrict__ acc, int n) {
    __shared__ int lhist[NCOARSE];   // 1 KB
    __shared__ int lbase[NCOARSE];   // 1 KB
    __shared__ int lcur[NCOARSE];    // 1 KB
    __shared__ int gbase[NCOARSE];   // 1 KB
    __shared__ int sc[256];          // 1 KB
    __shared__ uint4 stg[CHUNK];     // 32 KB
    __shared__ float lmom[4][27];

    const int tid = threadIdx.x;
    const int chunkStart = blockIdx.x * CHUNK;
    const int chunkCount = min(CHUNK, n - chunkStart);

    lhist[tid] = 0;
    __syncthreads();

    float s[27];
#pragma unroll
    for (int k = 0; k < 27; ++k) s[k] = 0.f;

    // phase 1: load idx+x, moments, pack records, LDS histogram
    int cellr[8];
    unsigned u0[8], u1[8], u2[8];
#pragma unroll
    for (int r = 0; r < 8; ++r) {
        const int i = r * 256 + tid;
        cellr[r] = -1;
        if (i < chunkCount) {
            const int p = chunkStart + i;
            const int2 ij = ((const int2*)idx)[p];
            const int cell = ij.x * N_PY + ij.y;
            cellr[r] = cell;
            const float2* xp = (const float2*)(x + (size_t)p * 6);
            const float2 a = xp[0], b2 = xp[1], c = xp[2];
            const float v6[6] = {a.x, a.y, b2.x, b2.y, c.x, c.y};
#pragma unroll
            for (int j = 0; j < 6; ++j) s[j] += v6[j];
            int k = 6;
#pragma unroll
            for (int i2 = 0; i2 < 6; ++i2)
#pragma unroll
                for (int j = i2; j < 6; ++j) { s[k] += v6[i2] * v6[j]; ++k; }
            u0[r] = pack2h(a.x, a.y);
            u1[r] = pack2h(b2.x, b2.y);
            u2[r] = pack2h(c.x, c.y);
            atomicAdd(&lhist[cell >> 10], 1);
        }
    }
    __syncthreads();

    // phase 2: local exclusive scan + reserve global ranges
    const int v = lhist[tid];
    sc[tid] = v;
    __syncthreads();
#pragma unroll
    for (int off = 1; off < 256; off <<= 1) {
        const int add = (tid >= off) ? sc[tid - off] : 0;
        __syncthreads();
        sc[tid] += add;
        __syncthreads();
    }
    const int excl = sc[tid] - v;
    lbase[tid] = excl;
    lcur[tid] = excl;
    gbase[tid] = (v > 0) ? atomicAdd(&curC[tid], v) : 0;
    __syncthreads();

    // phase 3: rank records into the coarse-grouped LDS stage
#pragma unroll
    for (int r = 0; r < 8; ++r) {
        const int cell = cellr[r];
        if (cell >= 0) {
            const int slot = atomicAdd(&lcur[cell >> 10], 1);
            stg[slot] = uint4{u0[r], u1[r], u2[r], (unsigned)cell};
        }
    }
    __syncthreads();

    // phase 4: write out in staged order -> contiguous global runs
#pragma unroll
    for (int r = 0; r < 8; ++r) {
        const int slot = r * 256 + tid;
        if (slot < chunkCount) {
            const uint4 q = stg[slot];
            const int bkt = (int)(q.w >> 10);
            const int dst = gbase[bkt] + (slot - lbase[bkt]);
            rec[dst] = q;
        }
    }

    // moments: wave reduce -> cross-wave LDS -> 27 global atomics per block
#pragma unroll
    for (int off = 32; off > 0; off >>= 1)
#pragma unroll
        for (int k = 0; k < 27; ++k) s[k] += __shfl_down(s[k], off, 64);
    const int wid = tid >> 6;
    const int lane = tid & 63;
    if (lane == 0)
#pragma unroll
        for (int k = 0; k < 27; ++k) lmom[wid][k] = s[k];
    __syncthreads();
    if (tid < 27) {
        const int k = tid;
        atomicAdd(&acc[k], lmom[0][k] + lmom[1][k] + lmom[2][k] + lmom[3][k]);
    }
}

// ---- 4) passB: SINGLE-PASS fine scatter within single-owner windows + BN ----
__global__ void __launch_bounds__(256)
pfn_passB_kernel(const uint4* __restrict__ rec, uint4* __restrict__ rec2,
                 const int* __restrict__ S, int n,
                 const float* __restrict__ acc,
                 const float* __restrict__ W,
                 const float* __restrict__ b,
                 const float* __restrict__ gamma,
                 const float* __restrict__ beta,
                 float* __restrict__ Wp, float* __restrict__ bp) {
    __shared__ int lc[64];
    const int tid = threadIdx.x;
    const int c = blockIdx.x;
    const int segbase = S[c * 64];
    const int cnt = S[(c + 1) * 64] - segbase;   // c=255 hits sentinel via S[16384]

    // cursors straight from the global fine scan (only block c touches them)
    if (tid < 64) lc[tid] = S[c * 64 + tid];

    // BN fold on block 0 lanes 64..127 (acc complete: passA finished).
    if (c == 0 && tid >= 64 && tid < 128) {
        const int f = tid - 64;
        double inv_n = 1.0 / (double)n;
        double mx[6];
#pragma unroll
        for (int j = 0; j < 6; ++j) mx[j] = (double)acc[j] * inv_n;
        double C[6][6];
        {
            int k = 0;
            for (int i = 0; i < 6; ++i)
                for (int j = i; j < 6; ++j) {
                    double e = (double)acc[6 + k] * inv_n - mx[i] * mx[j];
                    C[i][j] = e; C[j][i] = e; ++k;
                }
        }
        double w[6];
#pragma unroll
        for (int j = 0; j < 6; ++j) w[j] = (double)W[f * 6 + j];
        double mean_h = (double)b[f];
#pragma unroll
        for (int j = 0; j < 6; ++j) mean_h += w[j] * mx[j];
        double var_h = 0.0;
        for (int i = 0; i < 6; ++i) {
            double tt = 0.0;
            for (int j = 0; j < 6; ++j) tt += C[i][j] * w[j];
            var_h += w[i] * tt;
        }
        double sgn = (double)gamma[f] / sqrt(var_h + BN_EPS);
#pragma unroll
        for (int j = 0; j < 6; ++j) Wp[f * 6 + j] = (float)(w[j] * sgn);
        bp[f] = (float)(((double)b[f] - mean_h) * sgn + (double)beta[f]);
    }
    __syncthreads();

    // single pass: read coarse-grouped records, scatter into fine order
    // within the block-owned (L2-resident) window
    for (int i = tid; i < cnt; i += 256) {
        const uint4 q = rec[segbase + i];
        const int fine = (int)((((q.w >> 6) & 15) << 2) | (q.w & 3));
        const int pos = atomicAdd(&lc[fine], 1);
        rec2[pos] = q;
    }
}

// ---- 5) tile: one block per 64-cell bucket, 4 waves (class-exclusive),
// LDS-staged coalesced record loads, plain LDS +=, 16KB coalesced flush ----
__global__ void __launch_bounds__(256)
pfn_tile_kernel(const uint4* __restrict__ rec2, const int* __restrict__ S,
                const float* __restrict__ Wp, const float* __restrict__ bp,
                float* __restrict__ out) {
    __shared__ float tile[64 * OUT_F];    // 16 KB
    __shared__ uint4 stage[4][64];        // 4 KB
    const int tid = threadIdx.x;
    const int lane = tid & 63;
    const int wid = tid >> 6;
    const int bucket = blockIdx.x;

    float4* t4 = (float4*)tile;
#pragma unroll
    for (int i = 0; i < 4; ++i)
        t4[tid + 256 * i] = float4{0.f, 0.f, 0.f, 0.f};

    const float w0 = Wp[lane * 6 + 0];
    const float w1 = Wp[lane * 6 + 1];
    const float w2 = Wp[lane * 6 + 2];
    const float w3 = Wp[lane * 6 + 3];
    const float w4 = Wp[lane * 6 + 4];
    const float w5 = Wp[lane * 6 + 5];
    const float bb = bp[lane];

    __syncthreads();

    const int sb = (bucket << 2) | wid;   // wave w owns cells with (cell&3)==w
    const int r0 = S[sb];
    const int cnt = S[sb + 1] - r0;
    uint4* stg = stage[wid];

    for (int chunk = 0; chunk < cnt; chunk += 64) {
        const int m = min(64, cnt - chunk);
        const uint4* src = rec2 + (size_t)(r0 + chunk);
        if (lane < m) stg[lane] = src[lane];   // coalesced 16B/lane
#pragma unroll 4
        for (int j = 0; j < m; ++j) {
            const uint4 q = stg[j];            // uniform ds_read: broadcast
            const float2 f01 = unpack2h(q.x);
            const float2 f23 = unpack2h(q.y);
            const float2 f45 = unpack2h(q.z);
            float v = bb;
            v = fmaf(w0, f01.x, v); v = fmaf(w1, f01.y, v);
            v = fmaf(w2, f23.x, v); v = fmaf(w3, f23.y, v);
            v = fmaf(w4, f45.x, v); v = fmaf(w5, f45.y, v);
            tile[(((int)q.w & 63) << 6) | lane] += fmaxf(v, 0.f);
        }
    }
    __syncthreads();

    float4* o4 = (float4*)(out + (size_t)bucket * (64 * OUT_F));
#pragma unroll
    for (int i = 0; i < 4; ++i)
        o4[tid + 256 * i] = t4[tid + 256 * i];
}

// ---- fallback (linked-list path, small ws) ----
__global__ void __launch_bounds__(256)
pfn_moments_kernel(const float* __restrict__ x, int n, float* __restrict__ acc) {
    const int tid = blockIdx.x * blockDim.x + threadIdx.x;
    const int stride = gridDim.x * blockDim.x;
    const int npairs = n >> 1;

    float s[27];
#pragma unroll
    for (int k = 0; k < 27; ++k) s[k] = 0.f;

    for (int q = tid; q < npairs; q += stride) {
        const float4* base4 = (const float4*)(x + (size_t)q * 12);
        const float4 a = base4[0];
        const float4 b4 = base4[1];
        const float4 c4 = base4[2];
        const float p0[6] = {a.x, a.y, a.z, a.w, b4.x, b4.y};
        const float p1[6] = {b4.z, b4.w, c4.x, c4.y, c4.z, c4.w};
#pragma unroll
        for (int j = 0; j < 6; ++j) s[j] += p0[j] + p1[j];
        int k = 6;
#pragma unroll
        for (int i = 0; i < 6; ++i)
#pragma unroll
            for (int j = i; j < 6; ++j) {
                s[k] += p0[i] * p0[j] + p1[i] * p1[j];
                ++k;
            }
    }
    if ((n & 1) && tid == 0) {
        const float* p = x + (size_t)(n - 1) * 6;
        float v[6];
#pragma unroll
        for (int j = 0; j < 6; ++j) v[j] = p[j];
#pragma unroll
        for (int j = 0; j < 6; ++j) s[j] += v[j];
        int k = 6;
#pragma unroll
        for (int i = 0; i < 6; ++i)
#pragma unroll
            for (int j = i; j < 6; ++j) { s[k] += v[i] * v[j]; ++k; }
    }

#pragma unroll
    for (int off = 32; off > 0; off >>= 1)
#pragma unroll
        for (int k = 0; k < 27; ++k) s[k] += __shfl_down(s[k], off, 64);

    __shared__ float lds[4][27];
    const int wid = threadIdx.x >> 6;
    const int lane = threadIdx.x & 63;
    if (lane == 0)
#pragma unroll
        for (int k = 0; k < 27; ++k) lds[wid][k] = s[k];
    __syncthreads();

    if (threadIdx.x < 27) {
        const int k = threadIdx.x;
        atomicAdd(&acc[k], lds[0][k] + lds[1][k] + lds[2][k] + lds[3][k]);
    }
}

__global__ void pfn_finalize_kernel(const float* __restrict__ acc,
                                    const float* __restrict__ W,
                                    const float* __restrict__ b,
                                    const float* __restrict__ gamma,
                                    const float* __restrict__ beta,
                                    int n,
                                    float* __restrict__ Wp,
                                    float* __restrict__ bp) {
    int f = threadIdx.x;
    double inv_n = 1.0 / (double)n;
    double mx[6];
#pragma unroll
    for (int j = 0; j < 6; ++j) mx[j] = (double)acc[j] * inv_n;
    double C[6][6];
    {
        int k = 0;
        for (int i = 0; i < 6; ++i)
            for (int j = i; j < 6; ++j) {
                double e = (double)acc[6 + k] * inv_n - mx[i] * mx[j];
                C[i][j] = e; C[j][i] = e; ++k;
            }
    }
    double w[6];
#pragma unroll
    for (int j = 0; j < 6; ++j) w[j] = (double)W[f * 6 + j];
    double mean_h = (double)b[f];
#pragma unroll
    for (int j = 0; j < 6; ++j) mean_h += w[j] * mx[j];
    double var_h = 0.0;
    for (int i = 0; i < 6; ++i) {
        double t = 0.0;
        for (int j = 0; j < 6; ++j) t += C[i][j] * w[j];
        var_h += w[i] * t;
    }
    double s = (double)gamma[f] / sqrt(var_h + BN_EPS);
#pragma unroll
    for (int j = 0; j < 6; ++j) Wp[f * 6 + j] = (float)(w[j] * s);
    bp[f] = (float)(((double)b[f] - mean_h) * s + (double)beta[f]);
}

__global__ void __launch_bounds__(256)
pfn_build_kernel(const int* __restrict__ idx, int n,
                 int* __restrict__ head, int* __restrict__ nxt) {
    const int p = blockIdx.x * blockDim.x + threadIdx.x;
    if (p >= n) return;
    const int2 ij = ((const int2*)idx)[p];
    const int cell = ij.x * N_PY + ij.y;
    nxt[p] = atomicExch(&head[cell], p);
}

__global__ void __launch_bounds__(256)
pfn_output_kernel(const float* __restrict__ x,
                  const int* __restrict__ head,
                  const int* __restrict__ nxt,
                  const float* __restrict__ Wp,
                  const float* __restrict__ bp,
                  float* __restrict__ out) {
    const int lane = threadIdx.x & 63;
    const int cell = __builtin_amdgcn_readfirstlane(
        (int)((blockIdx.x * blockDim.x + threadIdx.x) >> 6));

    const float w0 = Wp[lane * 6 + 0];
    const float w1 = Wp[lane * 6 + 1];
    const float w2 = Wp[lane * 6 + 2];
    const float w3 = Wp[lane * 6 + 3];
    const float w4 = Wp[lane * 6 + 4];
    const float w5 = Wp[lane * 6 + 5];
    const float bb = bp[lane];

    float s = 0.f;
    int p = head[cell];
    while (p >= 0) {
        const float* xp = x + (size_t)p * 6;
        const int pn = nxt[p];
        float v = bb;
        v = fmaf(w0, xp[0], v);
        v = fmaf(w1, xp[1], v);
        v = fmaf(w2, xp[2], v);
        v = fmaf(w3, xp[3], v);
        v = fmaf(w4, xp[4], v);
        v = fmaf(w5, xp[5], v);
        s += fmaxf(v, 0.0f);
        p = pn;
    }
    out[(size_t)cell * OUT_F + lane] = s;
}

extern "C" void kernel_launch(void* const* d_in, const int* in_sizes, int n_in,
                              void* d_out, int out_size, void* d_ws, size_t ws_size,
                              hipStream_t stream) {
    const float* x     = (const float*)d_in[0];
    const int*   idx   = (const int*)d_in[1];
    const float* W     = (const float*)d_in[2];
    const float* b     = (const float*)d_in[3];
    const float* gamma = (const float*)d_in[4];
    const float* beta  = (const float*)d_in[5];
    float* out = (float*)d_out;

    const int n = in_sizes[0] / IN_F;

    float* acc = (float*)d_ws;
    float* Wp  = (float*)((char*)d_ws + 512);
    float* bp  = Wp + OUT_F * IN_F;

    int*   H16  = (int*)((char*)d_ws + 4096);      // 16384 ints
    int*   S    = (int*)((char*)d_ws + 69632);     // 16385 ints
    int*   curC = (int*)((char*)d_ws + 135680);    // 256 ints
    uint4* rec  = (uint4*)((char*)d_ws + 139264);
    uint4* rec2 = rec + n;

    const size_t need = 139264 + (size_t)n * 32;

    if (ws_size >= need) {
        // zero acc + H16 (68 KB; S/curC fully rewritten by scan kernel)
        hipMemsetAsync(d_ws, 0, 69632, stream);
        pfn_hist16_kernel<<<1024, 256, 0, stream>>>(idx, n, H16);
        pfn_scan16_kernel<<<1, 1024, 0, stream>>>(H16, S, curC, n);
        pfn_passA_kernel<<<(n + CHUNK - 1) / CHUNK, 256, 0, stream>>>(
            x, idx, curC, rec, acc, n);
        pfn_passB_kernel<<<NCOARSE, 256, 0, stream>>>(
            rec, rec2, S, n, acc, W, b, gamma, beta, Wp, bp);
        pfn_tile_kernel<<<NBUCKET, 256, 0, stream>>>(rec2, S, Wp, bp, out);
    } else {
        // linked-list fallback
        int* head = (int*)((char*)d_ws + 4096);
        int* nxt  = head + N_CELLS;
        hipMemsetAsync(d_ws, 0, 512, stream);
        pfn_moments_kernel<<<1024, 256, 0, stream>>>(x, n, acc);
        hipMemsetAsync(head, 0xFF, (size_t)N_CELLS * sizeof(int), stream);
        pfn_finalize_kernel<<<1, 64, 0, stream>>>(acc, W, b, gamma, beta, n, Wp, bp);
        pfn_build_kernel<<<(n + 255) / 256, 256, 0, stream>>>(idx, n, head, nxt);
        pfn_output_kernel<<<N_CELLS / 4, 256, 0, stream>>>(x, head, nxt, Wp, bp, out);
    }
}

// Round 15
// 86.731 us; speedup vs baseline: 1.3544x; 1.3544x over previous
//
#include <hip/hip_runtime.h>
#include <hip/hip_fp16.h>

#define N_PY 512
#define IN_F 6
#define OUT_F 64
#define N_CELLS (512 * 512)
#define NCOARSE 256               // coarse bucket = cell >> 10 (1024 cells)
#define NBUCKET 4096              // tile bucket  = cell >> 6   (64 cells)
#define N_SB (NBUCKET * 4)        // (bucket, class) segments = 16384
#define CHUNK 2048                // points per passA block
#define BN_EPS 1e-5

// ---------------------------------------------------------------------------
// ws layout:
//   [0, 108)       : 27 floats — moment accumulators (written by passA)
//   [512, 2304)    : float Wp[64*6], float bp[64] — BN-folded params (passB)
//   [4096, 5120)   : int histC[256]  — coarse counts (pristine)
//   [5120, 6144)   : int baseC[256]  — coarse exclusive scan (pristine)
//   [6144, 7168)   : int curC[256]   — mutable cursor for passA
//   [7168, 72708)  : int S[16385]    — fine segment starts (passB) + sentinel
//   [73728, +16n)  : uint4 rec[n]    — coarse-grouped 16B records
//   [73728+16n, +16n): uint4 rec2[n] — fine-sorted records
// R14 lesson: a streaming 16MB re-read (passB's fine-hist pre-pass) is
// CHEAPER than 1M uncoalesced global atomics (global fine histogram) —
// keep the coarse LDS-pre-agg hist + per-block fine hist structure.
// ---------------------------------------------------------------------------

__device__ __forceinline__ unsigned pack2h(float a, float b) {
    __half ha = __float2half_rn(a), hb = __float2half_rn(b);
    unsigned short ua = *reinterpret_cast<unsigned short*>(&ha);
    unsigned short ub = *reinterpret_cast<unsigned short*>(&hb);
    return (unsigned)ua | ((unsigned)ub << 16);
}

__device__ __forceinline__ float2 unpack2h(unsigned u) {
    __half2 h = *reinterpret_cast<__half2*>(&u);
    return __half22float2(h);
}

// ---- 1) coarse histogram from idx only (LDS pre-aggregated) ----
__global__ void __launch_bounds__(256)
pfn_hist_kernel(const int* __restrict__ idx, int n, int* __restrict__ histC) {
    __shared__ int lhist[NCOARSE];
    const int tid = blockIdx.x * blockDim.x + threadIdx.x;
    const int stride = gridDim.x * blockDim.x;
    const int npairs = n >> 1;

    lhist[threadIdx.x] = 0;
    __syncthreads();

    for (int q = tid; q < npairs; q += stride) {
        const int4 ij2 = ((const int4*)idx)[q];
        atomicAdd(&lhist[(ij2.x * N_PY + ij2.y) >> 10], 1);
        atomicAdd(&lhist[(ij2.z * N_PY + ij2.w) >> 10], 1);
    }
    if ((n & 1) && tid == 0) {
        const int2 ij = ((const int2*)idx)[n - 1];
        atomicAdd(&lhist[(ij.x * N_PY + ij.y) >> 10], 1);
    }
    __syncthreads();
    atomicAdd(&histC[threadIdx.x], lhist[threadIdx.x]);
}

// ---- 2) coarse scan + S sentinel (1 block, 256 threads) ----
__global__ void __launch_bounds__(256)
pfn_scan_kernel(const int* __restrict__ histC,
                int* __restrict__ baseC, int* __restrict__ curC,
                int* __restrict__ S, int n) {
    const int tid = threadIdx.x;
    const int v = histC[tid];
    __shared__ int sc[256];
    sc[tid] = v;
    __syncthreads();
#pragma unroll
    for (int off = 1; off < 256; off <<= 1) {
        const int add = (tid >= off) ? sc[tid - off] : 0;
        __syncthreads();
        sc[tid] += add;
        __syncthreads();
    }
    const int excl = sc[tid] - v;
    baseC[tid] = excl;
    curC[tid] = excl;
    if (tid == 0) S[N_SB] = n;   // sentinel for tile kernel
}

// ---- 3) passA: coarse LDS-staged partition + moment accumulation ----
// Each block: 2048 points. Records packed in registers, ranked into a 32KB
// LDS stage grouped by coarse bucket, written out as contiguous runs
// (~8 records = 128B per bucket per block). Moments accumulated on the
// exact f32 values already in registers (x is read ONCE total).
__global__ void __launch_bounds__(256)
pfn_passA_kernel(const float* __restrict__ x, const int* __restrict__ idx,
                 int* __restrict__ curC, uint4* __restrict__ rec,
                 float* __restrict__ acc, int n) {
    __shared__ int lhist[NCOARSE];   // 1 KB
    __shared__ int lbase[NCOARSE];   // 1 KB
    __shared__ int lcur[NCOARSE];    // 1 KB
    __shared__ int gbase[NCOARSE];   // 1 KB
    __shared__ int sc[256];          // 1 KB
    __shared__ uint4 stg[CHUNK];     // 32 KB
    __shared__ float lmom[4][27];

    const int tid = threadIdx.x;
    const int chunkStart = blockIdx.x * CHUNK;
    const int chunkCount = min(CHUNK, n - chunkStart);

    lhist[tid] = 0;
    __syncthreads();

    float s[27];
#pragma unroll
    for (int k = 0; k < 27; ++k) s[k] = 0.f;

    // phase 1: load idx+x, moments, pack records, LDS histogram
    int cellr[8];
    unsigned u0[8], u1[8], u2[8];
#pragma unroll
    for (int r = 0; r < 8; ++r) {
        const int i = r * 256 + tid;
        cellr[r] = -1;
        if (i < chunkCount) {
            const int p = chunkStart + i;
            const int2 ij = ((const int2*)idx)[p];
            const int cell = ij.x * N_PY + ij.y;
            cellr[r] = cell;
            const float2* xp = (const float2*)(x + (size_t)p * 6);
            const float2 a = xp[0], b2 = xp[1], c = xp[2];
            const float v6[6] = {a.x, a.y, b2.x, b2.y, c.x, c.y};
#pragma unroll
            for (int j = 0; j < 6; ++j) s[j] += v6[j];
            int k = 6;
#pragma unroll
            for (int i2 = 0; i2 < 6; ++i2)
#pragma unroll
                for (int j = i2; j < 6; ++j) { s[k] += v6[i2] * v6[j]; ++k; }
            u0[r] = pack2h(a.x, a.y);
            u1[r] = pack2h(b2.x, b2.y);
            u2[r] = pack2h(c.x, c.y);
            atomicAdd(&lhist[cell >> 10], 1);
        }
    }
    __syncthreads();

    // phase 2: local exclusive scan + reserve global ranges
    const int v = lhist[tid];
    sc[tid] = v;
    __syncthreads();
#pragma unroll
    for (int off = 1; off < 256; off <<= 1) {
        const int add = (tid >= off) ? sc[tid - off] : 0;
        __syncthreads();
        sc[tid] += add;
        __syncthreads();
    }
    const int excl = sc[tid] - v;
    lbase[tid] = excl;
    lcur[tid] = excl;
    gbase[tid] = (v > 0) ? atomicAdd(&curC[tid], v) : 0;
    __syncthreads();

    // phase 3: rank records into the coarse-grouped LDS stage
#pragma unroll
    for (int r = 0; r < 8; ++r) {
        const int cell = cellr[r];
        if (cell >= 0) {
            const int slot = atomicAdd(&lcur[cell >> 10], 1);
            stg[slot] = uint4{u0[r], u1[r], u2[r], (unsigned)cell};
        }
    }
    __syncthreads();

    // phase 4: write out in staged order -> contiguous global runs
#pragma unroll
    for (int r = 0; r < 8; ++r) {
        const int slot = r * 256 + tid;
        if (slot < chunkCount) {
            const uint4 q = stg[slot];
            const int bkt = (int)(q.w >> 10);
            const int dst = gbase[bkt] + (slot - lbase[bkt]);
            rec[dst] = q;
        }
    }

    // moments: wave reduce -> cross-wave LDS -> 27 global atomics per block
#pragma unroll
    for (int off = 32; off > 0; off >>= 1)
#pragma unroll
        for (int k = 0; k < 27; ++k) s[k] += __shfl_down(s[k], off, 64);
    const int wid = tid >> 6;
    const int lane = tid & 63;
    if (lane == 0)
#pragma unroll
        for (int k = 0; k < 27; ++k) lmom[wid][k] = s[k];
    __syncthreads();
    if (tid < 27) {
        const int k = tid;
        atomicAdd(&acc[k], lmom[0][k] + lmom[1][k] + lmom[2][k] + lmom[3][k]);
    }
}

// ---- 4) passB: fine sort within single-owner coarse windows + BN fold ----
__global__ void __launch_bounds__(256)
pfn_passB_kernel(const uint4* __restrict__ rec, uint4* __restrict__ rec2,
                 const int* __restrict__ baseC, const int* __restrict__ histC,
                 int* __restrict__ S, int n,
                 const float* __restrict__ acc,
                 const float* __restrict__ W,
                 const float* __restrict__ b,
                 const float* __restrict__ gamma,
                 const float* __restrict__ beta,
                 float* __restrict__ Wp, float* __restrict__ bp) {
    __shared__ int lh[64];
    __shared__ int lc[64];
    const int tid = threadIdx.x;
    const int c = blockIdx.x;
    const int segbase = baseC[c];
    const int cnt = histC[c];

    if (tid < 64) lh[tid] = 0;
    __syncthreads();

    // BN fold on block 0 lanes 0..63 (acc complete: passA finished).
    // Straight-line, no barriers inside -> other waves proceed to hist loop.
    if (c == 0 && tid < 64) {
        const int f = tid;
        double inv_n = 1.0 / (double)n;
        double mx[6];
#pragma unroll
        for (int j = 0; j < 6; ++j) mx[j] = (double)acc[j] * inv_n;
        double C[6][6];
        {
            int k = 0;
            for (int i = 0; i < 6; ++i)
                for (int j = i; j < 6; ++j) {
                    double e = (double)acc[6 + k] * inv_n - mx[i] * mx[j];
                    C[i][j] = e; C[j][i] = e; ++k;
                }
        }
        double w[6];
#pragma unroll
        for (int j = 0; j < 6; ++j) w[j] = (double)W[f * 6 + j];
        double mean_h = (double)b[f];
#pragma unroll
        for (int j = 0; j < 6; ++j) mean_h += w[j] * mx[j];
        double var_h = 0.0;
        for (int i = 0; i < 6; ++i) {
            double tt = 0.0;
            for (int j = 0; j < 6; ++j) tt += C[i][j] * w[j];
            var_h += w[i] * tt;
        }
        double sgn = (double)gamma[f] / sqrt(var_h + BN_EPS);
#pragma unroll
        for (int j = 0; j < 6; ++j) Wp[f * 6 + j] = (float)(w[j] * sgn);
        bp[f] = (float)(((double)b[f] - mean_h) * sgn + (double)beta[f]);
    }

    // phase 1: fine histogram (fine = ((cell>>6)&15)<<2 | (cell&3))
    for (int i = tid; i < cnt; i += 256) {
        const uint4 q = rec[segbase + i];
        const int fine = (int)((((q.w >> 6) & 15) << 2) | (q.w & 3));
        atomicAdd(&lh[fine], 1);
    }
    __syncthreads();

    // scan 64 entries in wave 0 via shfl; emit S
    if (tid < 64) {
        const int v = lh[tid];
        int incl = v;
#pragma unroll
        for (int off = 1; off < 64; off <<= 1) {
            const int t2 = __shfl_up(incl, off, 64);
            if (tid >= off) incl += t2;
        }
        const int excl = incl - v;
        lc[tid] = excl;
        S[c * 64 + tid] = segbase + excl;   // global sb = c*64 + fine
    }
    __syncthreads();

    // phase 2: scatter into fine order within the block-owned window
    for (int i = tid; i < cnt; i += 256) {
        const uint4 q = rec[segbase + i];
        const int fine = (int)((((q.w >> 6) & 15) << 2) | (q.w & 3));
        const int off = atomicAdd(&lc[fine], 1);
        rec2[segbase + off] = q;
    }
}

// ---- 5) tile: one block per 64-cell bucket, 4 waves (class-exclusive),
// LDS-staged coalesced record loads, plain LDS +=, 16KB coalesced flush ----
__global__ void __launch_bounds__(256)
pfn_tile_kernel(const uint4* __restrict__ rec2, const int* __restrict__ S,
                const float* __restrict__ Wp, const float* __restrict__ bp,
                float* __restrict__ out) {
    __shared__ float tile[64 * OUT_F];    // 16 KB
    __shared__ uint4 stage[4][64];        // 4 KB
    const int tid = threadIdx.x;
    const int lane = tid & 63;
    const int wid = tid >> 6;
    const int bucket = blockIdx.x;

    float4* t4 = (float4*)tile;
#pragma unroll
    for (int i = 0; i < 4; ++i)
        t4[tid + 256 * i] = float4{0.f, 0.f, 0.f, 0.f};

    const float w0 = Wp[lane * 6 + 0];
    const float w1 = Wp[lane * 6 + 1];
    const float w2 = Wp[lane * 6 + 2];
    const float w3 = Wp[lane * 6 + 3];
    const float w4 = Wp[lane * 6 + 4];
    const float w5 = Wp[lane * 6 + 5];
    const float bb = bp[lane];

    __syncthreads();

    const int sb = (bucket << 2) | wid;   // wave w owns cells with (cell&3)==w
    const int r0 = S[sb];
    const int cnt = S[sb + 1] - r0;
    uint4* stg = stage[wid];

    for (int chunk = 0; chunk < cnt; chunk += 64) {
        const int m = min(64, cnt - chunk);
        const uint4* src = rec2 + (size_t)(r0 + chunk);
        if (lane < m) stg[lane] = src[lane];   // coalesced 16B/lane
#pragma unroll 4
        for (int j = 0; j < m; ++j) {
            const uint4 q = stg[j];            // uniform ds_read: broadcast
            const float2 f01 = unpack2h(q.x);
            const float2 f23 = unpack2h(q.y);
            const float2 f45 = unpack2h(q.z);
            float v = bb;
            v = fmaf(w0, f01.x, v); v = fmaf(w1, f01.y, v);
            v = fmaf(w2, f23.x, v); v = fmaf(w3, f23.y, v);
            v = fmaf(w4, f45.x, v); v = fmaf(w5, f45.y, v);
            tile[(((int)q.w & 63) << 6) | lane] += fmaxf(v, 0.f);
        }
    }
    __syncthreads();

    float4* o4 = (float4*)(out + (size_t)bucket * (64 * OUT_F));
#pragma unroll
    for (int i = 0; i < 4; ++i)
        o4[tid + 256 * i] = t4[tid + 256 * i];
}

// ---- fallback (linked-list path, small ws) ----
__global__ void __launch_bounds__(256)
pfn_moments_kernel(const float* __restrict__ x, int n, float* __restrict__ acc) {
    const int tid = blockIdx.x * blockDim.x + threadIdx.x;
    const int stride = gridDim.x * blockDim.x;
    const int npairs = n >> 1;

    float s[27];
#pragma unroll
    for (int k = 0; k < 27; ++k) s[k] = 0.f;

    for (int q = tid; q < npairs; q += stride) {
        const float4* base4 = (const float4*)(x + (size_t)q * 12);
        const float4 a = base4[0];
        const float4 b4 = base4[1];
        const float4 c4 = base4[2];
        const float p0[6] = {a.x, a.y, a.z, a.w, b4.x, b4.y};
        const float p1[6] = {b4.z, b4.w, c4.x, c4.y, c4.z, c4.w};
#pragma unroll
        for (int j = 0; j < 6; ++j) s[j] += p0[j] + p1[j];
        int k = 6;
#pragma unroll
        for (int i = 0; i < 6; ++i)
#pragma unroll
            for (int j = i; j < 6; ++j) {
                s[k] += p0[i] * p0[j] + p1[i] * p1[j];
                ++k;
            }
    }
    if ((n & 1) && tid == 0) {
        const float* p = x + (size_t)(n - 1) * 6;
        float v[6];
#pragma unroll
        for (int j = 0; j < 6; ++j) v[j] = p[j];
#pragma unroll
        for (int j = 0; j < 6; ++j) s[j] += v[j];
        int k = 6;
#pragma unroll
        for (int i = 0; i < 6; ++i)
#pragma unroll
            for (int j = i; j < 6; ++j) { s[k] += v[i] * v[j]; ++k; }
    }

#pragma unroll
    for (int off = 32; off > 0; off >>= 1)
#pragma unroll
        for (int k = 0; k < 27; ++k) s[k] += __shfl_down(s[k], off, 64);

    __shared__ float lds[4][27];
    const int wid = threadIdx.x >> 6;
    const int lane = threadIdx.x & 63;
    if (lane == 0)
#pragma unroll
        for (int k = 0; k < 27; ++k) lds[wid][k] = s[k];
    __syncthreads();

    if (threadIdx.x < 27) {
        const int k = threadIdx.x;
        atomicAdd(&acc[k], lds[0][k] + lds[1][k] + lds[2][k] + lds[3][k]);
    }
}

__global__ void pfn_finalize_kernel(const float* __restrict__ acc,
                                    const float* __restrict__ W,
                                    const float* __restrict__ b,
                                    const float* __restrict__ gamma,
                                    const float* __restrict__ beta,
                                    int n,
                                    float* __restrict__ Wp,
                                    float* __restrict__ bp) {
    int f = threadIdx.x;
    double inv_n = 1.0 / (double)n;
    double mx[6];
#pragma unroll
    for (int j = 0; j < 6; ++j) mx[j] = (double)acc[j] * inv_n;
    double C[6][6];
    {
        int k = 0;
        for (int i = 0; i < 6; ++i)
            for (int j = i; j < 6; ++j) {
                double e = (double)acc[6 + k] * inv_n - mx[i] * mx[j];
                C[i][j] = e; C[j][i] = e; ++k;
            }
    }
    double w[6];
#pragma unroll
    for (int j = 0; j < 6; ++j) w[j] = (double)W[f * 6 + j];
    double mean_h = (double)b[f];
#pragma unroll
    for (int j = 0; j < 6; ++j) mean_h += w[j] * mx[j];
    double var_h = 0.0;
    for (int i = 0; i < 6; ++i) {
        double t = 0.0;
        for (int j = 0; j < 6; ++j) t += C[i][j] * w[j];
        var_h += w[i] * t;
    }
    double s = (double)gamma[f] / sqrt(var_h + BN_EPS);
#pragma unroll
    for (int j = 0; j < 6; ++j) Wp[f * 6 + j] = (float)(w[j] * s);
    bp[f] = (float)(((double)b[f] - mean_h) * s + (double)beta[f]);
}

__global__ void __launch_bounds__(256)
pfn_build_kernel(const int* __restrict__ idx, int n,
                 int* __restrict__ head, int* __restrict__ nxt) {
    const int p = blockIdx.x * blockDim.x + threadIdx.x;
    if (p >= n) return;
    const int2 ij = ((const int2*)idx)[p];
    const int cell = ij.x * N_PY + ij.y;
    nxt[p] = atomicExch(&head[cell], p);
}

__global__ void __launch_bounds__(256)
pfn_output_kernel(const float* __restrict__ x,
                  const int* __restrict__ head,
                  const int* __restrict__ nxt,
                  const float* __restrict__ Wp,
                  const float* __restrict__ bp,
                  float* __restrict__ out) {
    const int lane = threadIdx.x & 63;
    const int cell = __builtin_amdgcn_readfirstlane(
        (int)((blockIdx.x * blockDim.x + threadIdx.x) >> 6));

    const float w0 = Wp[lane * 6 + 0];
    const float w1 = Wp[lane * 6 + 1];
    const float w2 = Wp[lane * 6 + 2];
    const float w3 = Wp[lane * 6 + 3];
    const float w4 = Wp[lane * 6 + 4];
    const float w5 = Wp[lane * 6 + 5];
    const float bb = bp[lane];

    float s = 0.f;
    int p = head[cell];
    while (p >= 0) {
        const float* xp = x + (size_t)p * 6;
        const int pn = nxt[p];
        float v = bb;
        v = fmaf(w0, xp[0], v);
        v = fmaf(w1, xp[1], v);
        v = fmaf(w2, xp[2], v);
        v = fmaf(w3, xp[3], v);
        v = fmaf(w4, xp[4], v);
        v = fmaf(w5, xp[5], v);
        s += fmaxf(v, 0.0f);
        p = pn;
    }
    out[(size_t)cell * OUT_F + lane] = s;
}

extern "C" void kernel_launch(void* const* d_in, const int* in_sizes, int n_in,
                              void* d_out, int out_size, void* d_ws, size_t ws_size,
                              hipStream_t stream) {
    const float* x     = (const float*)d_in[0];
    const int*   idx   = (const int*)d_in[1];
    const float* W     = (const float*)d_in[2];
    const float* b     = (const float*)d_in[3];
    const float* gamma = (const float*)d_in[4];
    const float* beta  = (const float*)d_in[5];
    float* out = (float*)d_out;

    const int n = in_sizes[0] / IN_F;

    float* acc = (float*)d_ws;
    float* Wp  = (float*)((char*)d_ws + 512);
    float* bp  = Wp + OUT_F * IN_F;

    int*   histC = (int*)((char*)d_ws + 4096);
    int*   baseC = (int*)((char*)d_ws + 5120);
    int*   curC  = (int*)((char*)d_ws + 6144);
    int*   S     = (int*)((char*)d_ws + 7168);    // 16385 ints
    uint4* rec   = (uint4*)((char*)d_ws + 73728);
    uint4* rec2  = rec + n;

    const size_t need = 73728 + (size_t)n * 32;

    if (ws_size >= need) {
        // zero acc + histC (5 KB; everything else fully rewritten per call)
        hipMemsetAsync(d_ws, 0, 5120, stream);
        pfn_hist_kernel<<<256, 256, 0, stream>>>(idx, n, histC);
        pfn_scan_kernel<<<1, 256, 0, stream>>>(histC, baseC, curC, S, n);
        pfn_passA_kernel<<<(n + CHUNK - 1) / CHUNK, 256, 0, stream>>>(
            x, idx, curC, rec, acc, n);
        pfn_passB_kernel<<<NCOARSE, 256, 0, stream>>>(
            rec, rec2, baseC, histC, S, n, acc, W, b, gamma, beta, Wp, bp);
        pfn_tile_kernel<<<NBUCKET, 256, 0, stream>>>(rec2, S, Wp, bp, out);
    } else {
        // linked-list fallback
        int* head = (int*)((char*)d_ws + 4096);
        int* nxt  = head + N_CELLS;
        hipMemsetAsync(d_ws, 0, 512, stream);
        pfn_moments_kernel<<<1024, 256, 0, stream>>>(x, n, acc);
        hipMemsetAsync(head, 0xFF, (size_t)N_CELLS * sizeof(int), stream);
        pfn_finalize_kernel<<<1, 64, 0, stream>>>(acc, W, b, gamma, beta, n, Wp, bp);
        pfn_build_kernel<<<(n + 255) / 256, 256, 0, stream>>>(idx, n, head, nxt);
        pfn_output_kernel<<<N_CELLS / 4, 256, 0, stream>>>(x, head, nxt, Wp, bp, out);
    }
}